// Round 2
// baseline (295.897 us; speedup 1.0000x reference)
//
#include <hip/hip_runtime.h>
#include <hip/hip_bf16.h>
#include <math.h>

#define B_SZ    1024
#define DI      2560
#define DS      16
#define DR      160
#define NPROJ   192   // DR + DS + DS

typedef __bf16 bf16x8 __attribute__((ext_vector_type(8)));
typedef float  f32x4  __attribute__((ext_vector_type(4)));

__device__ __forceinline__ float fast_exp2(float x) {
#if __has_builtin(__builtin_amdgcn_exp2f)
  return __builtin_amdgcn_exp2f(x);   // v_exp_f32
#else
  return exp2f(x);
#endif
}
__device__ __forceinline__ float fast_log2(float x) {
#if __has_builtin(__builtin_amdgcn_logf)
  return __builtin_amdgcn_logf(x);    // v_log_f32
#else
  return log2f(x);
#endif
}

#define LOG2E 1.44269504088896f
#define LN2   0.693147180559945f

// ---------------- kernel 0: fp32 -> bf16 conversions + negA2 = -exp(A_log)*log2e
__global__ void __launch_bounds__(256) convert_kernel(
    const float* __restrict__ x, const float* __restrict__ Wdl,
    const float* __restrict__ WB, const float* __restrict__ WC,
    const float* __restrict__ Wdt, const float* __restrict__ A_log,
    __bf16* __restrict__ xb, __bf16* __restrict__ wcat,
    __bf16* __restrict__ wdtb, float* __restrict__ negA2) {
  int i = blockIdx.x * 256 + threadIdx.x;
  const int NX   = B_SZ * DI;   // 2621440
  const int NWDL = DR * DI;     // 409600
  const int NWB  = DS * DI;     // 40960
  const int NWDT = DI * DR;     // 409600
  const int NA   = DI * DS;     // 40960
  if (i < NX)   { xb[i] = (__bf16)x[i]; return; }
  i -= NX;
  if (i < NWDL) { wcat[i] = (__bf16)Wdl[i]; return; }
  i -= NWDL;
  if (i < NWB)  { wcat[NWDL + i] = (__bf16)WB[i]; return; }
  i -= NWB;
  if (i < NWB)  { wcat[NWDL + NWB + i] = (__bf16)WC[i]; return; }
  i -= NWB;
  if (i < NWDT) { wdtb[i] = (__bf16)Wdt[i]; return; }
  i -= NWDT;
  if (i < NA)   { negA2[i] = -fast_exp2(A_log[i] * LOG2E) * LOG2E; }
}

// ---------------- kernel 1: proj GEMM  C[1024,192] = xb . wcat^T -------------
// one wave per 16x16 tile, K=2560 in 80 MFMA steps; 768 blocks x 64 thr
__global__ void __launch_bounds__(64) proj_kernel(
    const __bf16* __restrict__ xb, const __bf16* __restrict__ wcat,
    __bf16* __restrict__ dtlow, float* __restrict__ Bt, float* __restrict__ Ct) {
  int gw    = blockIdx.x;                  // 768 wave-tiles
  int lane  = threadIdx.x;                 // 0..63
  int mtile = gw & 63;                     // 64 m-tiles of 16
  int ntile = gw >> 6;                     // 12 n-tiles of 16
  int b0 = mtile * 16, n0 = ntile * 16;
  int m = lane & 15, quad = lane >> 4;
  const __bf16* ap = xb   + (size_t)(b0 + m) * DI + quad * 8;
  const __bf16* bp = wcat + (size_t)(n0 + m) * DI + quad * 8;
  f32x4 acc = {0.f, 0.f, 0.f, 0.f};
#pragma unroll 4
  for (int k0 = 0; k0 < DI; k0 += 32) {
    bf16x8 a = *(const bf16x8*)(ap + k0);
    bf16x8 b = *(const bf16x8*)(bp + k0);
    acc = __builtin_amdgcn_mfma_f32_16x16x32_bf16(a, b, acc, 0, 0, 0);
  }
  // D layout: col = lane&15 (n), row = quad*4 + r (m)
  int nn = n0 + m;
#pragma unroll
  for (int r = 0; r < 4; ++r) {
    int bb = b0 + quad * 4 + r;
    float v = acc[r];
    if (nn < DR)            dtlow[bb * DR + nn] = (__bf16)v;
    else if (nn < DR + DS)  Bt[bb * DS + (nn - DR)] = v;
    else                    Ct[bb * DS + (nn - DR - DS)] = v;
  }
}

// ---------------- kernel 2: fused dt GEMM + softplus + SSM state pass --------
// per wave: 16x16 (b,d) tile. MFMA gives dt_raw; lane owns 4 (b,d) pairs
// (bb = b0+quad*4+r, dd = d0+(lane&15)) and runs the state update for them.
__global__ void __launch_bounds__(256) dtssm_kernel(
    const __bf16* __restrict__ dtlow, const __bf16* __restrict__ wdtb,
    const float* __restrict__ b_dt, const float* __restrict__ x,
    const float* __restrict__ h, const float* __restrict__ negA2,
    const float* __restrict__ Bt, const float* __restrict__ Ct,
    const float* __restrict__ Dp, float* __restrict__ y) {
  int gw    = blockIdx.x * 4 + (threadIdx.x >> 6);   // 10240 wave-tiles
  int lane  = threadIdx.x & 63;
  int mtile = gw & 63;       // 64 b-tiles
  int ntile = gw >> 6;       // 160 d-tiles
  int b0 = mtile * 16, d0 = ntile * 16;
  int m = lane & 15, quad = lane >> 4;

  // --- dt GEMM: K=160 in 5 MFMA steps
  const __bf16* ap = dtlow + (size_t)(b0 + m) * DR + quad * 8;
  const __bf16* bp = wdtb  + (size_t)(d0 + m) * DR + quad * 8;
  f32x4 acc = {0.f, 0.f, 0.f, 0.f};
#pragma unroll
  for (int k0 = 0; k0 < DR; k0 += 32) {
    bf16x8 a = *(const bf16x8*)(ap + k0);
    bf16x8 b = *(const bf16x8*)(bp + k0);
    acc = __builtin_amdgcn_mfma_f32_16x16x32_bf16(a, b, acc, 0, 0, 0);
  }

  int dd = d0 + m;
  float bias = b_dt[dd];
  float dv   = Dp[dd];
  // negA2 row depends only on dd: load once (already has log2e folded in)
  const float4* a4 = (const float4*)(negA2 + (size_t)dd * DS);
  float4 av0 = a4[0], av1 = a4[1], av2 = a4[2], av3 = a4[3];

#pragma unroll
  for (int r = 0; r < 4; ++r) {
    int bb = b0 + quad * 4 + r;
    // softplus(z) = ln(1 + e^z) = log2(1 + 2^(z*log2e)) * ln2
    float z = acc[r] + bias;
    float t = fast_exp2(z * LOG2E);
    float dt = (z > 80.f) ? z : fast_log2(1.f + t) * LN2;

    size_t e = (size_t)bb * DI + dd;
    float xv  = x[e];
    float dxv = dt * xv;
    const float4* h4 = (const float4*)(h  + e * DS);
    const float4* b4 = (const float4*)(Bt + (size_t)bb * DS);
    const float4* c4 = (const float4*)(Ct + (size_t)bb * DS);
    float s = 0.f;
#pragma unroll
    for (int j = 0; j < 4; ++j) {
      float4 hv = h4[j], bv = b4[j], cv = c4[j];
      float4 avj = (j == 0) ? av0 : (j == 1) ? av1 : (j == 2) ? av2 : av3;
      s += (fast_exp2(avj.x * dt) * hv.x + bv.x * dxv) * cv.x;
      s += (fast_exp2(avj.y * dt) * hv.y + bv.y * dxv) * cv.y;
      s += (fast_exp2(avj.z * dt) * hv.z + bv.z * dxv) * cv.z;
      s += (fast_exp2(avj.w * dt) * hv.w + bv.w * dxv) * cv.w;
    }
    y[e] = s + dv * xv;
  }
}

extern "C" void kernel_launch(void* const* d_in, const int* in_sizes, int n_in,
                              void* d_out, int out_size, void* d_ws, size_t ws_size,
                              hipStream_t stream) {
  const float* x     = (const float*)d_in[0];
  const float* h     = (const float*)d_in[1];
  const float* Wdl   = (const float*)d_in[2];
  const float* Wdt   = (const float*)d_in[3];
  const float* b_dt  = (const float*)d_in[4];
  const float* WB    = (const float*)d_in[5];
  const float* WC    = (const float*)d_in[6];
  const float* A_log = (const float*)d_in[7];
  const float* Dp    = (const float*)d_in[8];
  float* y = (float*)d_out;

  // workspace layout (256B-aligned offsets)
  char* ws = (char*)d_ws;
  __bf16* xb    = (__bf16*)(ws);                       // 5,242,880 B
  __bf16* wcat  = (__bf16*)(ws + 5242880);             //   983,040 B
  __bf16* wdtb  = (__bf16*)(ws + 6225920);             //   819,200 B
  float*  negA2 = (float*) (ws + 7045120);             //   163,840 B
  __bf16* dtlow = (__bf16*)(ws + 7208960);             //   327,680 B
  float*  Bt    = (float*) (ws + 7536640);             //    65,536 B
  float*  Ct    = (float*) (ws + 7602176);             //    65,536 B -> 7,667,712 total
  if (ws_size < 7667712) return;

  // k0: conversions. 3,563,520 elems
  convert_kernel<<<13920, 256, 0, stream>>>(x, Wdl, WB, WC, Wdt, A_log,
                                            xb, wcat, wdtb, negA2);
  // k1: 768 one-wave blocks (spread over all CUs)
  proj_kernel<<<768, 64, 0, stream>>>(xb, wcat, dtlow, Bt, Ct);
  // k2: fused dt GEMM + ssm. 10240 wave-tiles / 4 per block
  dtssm_kernel<<<2560, 256, 0, stream>>>(dtlow, wdtb, b_dt, x, h, negA2,
                                         Bt, Ct, Dp, y);
}